// Round 4
// baseline (1279.650 us; speedup 1.0000x reference)
//
#include <hip/hip_runtime.h>
#include <cstddef>
#include <cstdint>

// B=32 C=192 H=W=64 HEADS=6 WS=8 SHIFT=4 P=8 EMB=640 HID=768 GROUPS=32
#define SCALE_Q 0.17677669529663688f

typedef __attribute__((ext_vector_type(8))) short short8;
typedef __attribute__((ext_vector_type(4))) float f32x4;

__device__ __forceinline__ float gelu_(float x) {
  return 0.5f * x * (1.f + erff(x * 0.70710678118654752f));
}
__device__ __forceinline__ ushort f2b(float x) {
  uint u = __float_as_uint(x);
  return (ushort)((u + 0x7FFFu + ((u >> 16) & 1u)) >> 16);
}

// ------------------- K0: s = silu(t) @ ada_w.T + ada_b -------------------
__global__ void k_scales(const float* __restrict__ t,
                         const float* __restrict__ w_msa, const float* __restrict__ b_msa,
                         const float* __restrict__ w_mlp, const float* __restrict__ b_mlp,
                         float* __restrict__ S) {
  int b = blockIdx.x, sel = blockIdx.y;
  const float* W  = sel ? w_mlp : w_msa;
  const float* BV = sel ? b_mlp : b_msa;
  __shared__ float st[640];
  for (int i = threadIdx.x; i < 640; i += 64) {
    float v = t[b * 640 + i];
    st[i] = v / (1.f + __expf(-v));
  }
  __syncthreads();
  int f = threadIdx.x;
  if (f < 40) {
    float acc = BV[f];
    for (int e = 0; e < 640; e++) acc += st[e] * W[f * 640 + e];
    S[(sel * 32 + b) * 40 + f] = acc;
  }
}

// ------------------- K1: build M_b (64x64) from s (8x5) -------------------
__global__ void k_mbuild(const float* __restrict__ S, float* __restrict__ M) {
  int b = blockIdx.x, sel = blockIdx.y;
  __shared__ float sl[40];
  __shared__ float ct[8];
  if (threadIdx.x < 40) sl[threadIdx.x] = S[(sel * 32 + b) * 40 + threadIdx.x];
  if (threadIdx.x < 8) ct[threadIdx.x] = cosf(0.78539816339744831f * (float)threadIdx.x);
  __syncthreads();
  float* Mo = M + ((size_t)(sel * 32 + b)) * 4096;
  for (int e = threadIdx.x; e < 4096; e += 256) {
    int p = e >> 6, q = e & 63;
    int a = p >> 3, bb = p & 7, c = q >> 3, d = q & 7;
    int da = (a - c) & 7, db = (bb - d) & 7;
    float sgn = ((bb ^ d) & 1) ? -1.f : 1.f;
    float acc = 0.f;
#pragma unroll
    for (int u = 0; u < 8; u++) {
      acc += (sl[u * 5 + 0] + sgn * sl[u * 5 + 4]) * ct[(u * da) & 7];
      acc += 2.f * (sl[u * 5 + 1] * ct[(u * da + db) & 7]
                  + sl[u * 5 + 2] * ct[(u * da + 2 * db) & 7]
                  + sl[u * 5 + 3] * ct[(u * da + 3 * db) & 7]);
    }
    Mo[e] = acc * 0.015625f;
  }
}

// ------------------- K2: weights fp32 -> bf16 -------------------
__global__ void k_f2b(const float* __restrict__ s0, const float* __restrict__ s1,
                      const float* __restrict__ s2, const float* __restrict__ s3,
                      ushort* __restrict__ d0, ushort* __restrict__ d1,
                      ushort* __restrict__ d2, ushort* __restrict__ d3) {
  int g = blockIdx.x * 256 + threadIdx.x;  // one float4 per thread
  const float* s; ushort* d; int off;
  if (g < 27648)       { s = s0; d = d0; off = g * 4; }
  else if (g < 36864)  { s = s1; d = d1; off = (g - 27648) * 4; }
  else if (g < 73728)  { s = s2; d = d2; off = (g - 36864) * 4; }
  else if (g < 110592) { s = s3; d = d3; off = (g - 73728) * 4; }
  else return;
  float4 v = *(const float4*)(s + off);
  ushort4 o = {f2b(v.x), f2b(v.y), f2b(v.z), f2b(v.w)};
  *(ushort4*)(d + off) = o;
}

// ------------------- K3: GroupNorm stats -------------------
__global__ void k_gnstats(const float* __restrict__ X, float* __restrict__ stats) {
  int bg = blockIdx.x;
  const float* base = X + (size_t)bg * 24576;
  float s = 0.f, ss = 0.f;
  for (int i = threadIdx.x; i < 24576; i += 256) {
    float v = base[i];
    s += v; ss += v * v;
  }
  for (int o = 32; o; o >>= 1) { s += __shfl_down(s, o); ss += __shfl_down(ss, o); }
  __shared__ float red[8];
  int wv = threadIdx.x >> 6;
  if ((threadIdx.x & 63) == 0) { red[wv] = s; red[4 + wv] = ss; }
  __syncthreads();
  if (threadIdx.x == 0) {
    float Sv = red[0] + red[1] + red[2] + red[3];
    float SS = red[4] + red[5] + red[6] + red[7];
    float mean = Sv * (1.f / 24576.f);
    float var = SS * (1.f / 24576.f) - mean * mean;
    stats[bg * 2] = mean;
    stats[bg * 2 + 1] = rsqrtf(var + 1e-5f);
  }
}

// ------------------- K4: fused GN-apply + AdaFM, bf16 plane out -------------------
__global__ __launch_bounds__(256) void k_gn_adafm(
    const float* __restrict__ X, const float* __restrict__ stats,
    const float* __restrict__ gw, const float* __restrict__ gb,
    const float* __restrict__ Mmat, ushort* __restrict__ Hout) {
  int c = blockIdx.x, b = blockIdx.y;
  __shared__ float Ms[64 * 68];
  __shared__ float Xs[64 * 68];
  const float* Mb = Mmat + (size_t)b * 4096;
  for (int i = threadIdx.x; i < 4096; i += 256) {
    int p = i >> 6, q = i & 63;
    Ms[q * 68 + p] = Mb[i];
  }
  int g = c / 6;
  float mean = stats[(b * 32 + g) * 2];
  float rstd = stats[(b * 32 + g) * 2 + 1];
  float gamma = gw[c], beta = gb[c];
  const float* plane = X + ((size_t)b * 192 + c) * 4096;
  for (int i = threadIdx.x; i < 4096; i += 256) {
    float v = (plane[i] - mean) * rstd * gamma + beta;
    int ph = i >> 9, a = (i >> 6) & 7, pw = (i >> 3) & 7, bb = i & 7;
    Xs[(a * 8 + bb) * 68 + (ph * 8 + pw)] = v;
  }
  __syncthreads();
  int tx = threadIdx.x & 15, ty = threadIdx.x >> 4;
  float acc[4][4] = {};
#pragma unroll
  for (int k = 0; k < 64; k++) {
    float4 a4 = *(const float4*)&Ms[k * 68 + ty * 4];
    float4 b4 = *(const float4*)&Xs[k * 68 + tx * 4];
    float ar[4] = {a4.x, a4.y, a4.z, a4.w};
    float br[4] = {b4.x, b4.y, b4.z, b4.w};
#pragma unroll
    for (int i = 0; i < 4; i++)
#pragma unroll
      for (int j = 0; j < 4; j++)
        acc[i][j] = fmaf(ar[i], br[j], acc[i][j]);
  }
  __syncthreads();
#pragma unroll
  for (int i = 0; i < 4; i++)
#pragma unroll
    for (int j = 0; j < 4; j++)
      Xs[(ty * 4 + i) * 68 + tx * 4 + j] = acc[i][j];
  __syncthreads();
  ushort* oplane = Hout + ((size_t)b * 192 + c) * 4096;
  for (int ip = threadIdx.x; ip < 2048; ip += 256) {
    int i = ip << 1;
    int ph2 = i >> 9, a = (i >> 6) & 7, pw = (i >> 3) & 7, bb = i & 7;
    float v0 = Xs[(a * 8 + bb) * 68 + (ph2 * 8 + pw)];
    float v1 = Xs[(a * 8 + bb + 1) * 68 + (ph2 * 8 + pw)];
    uint pk = (uint)f2b(v0) | ((uint)f2b(v1) << 16);
    ((uint*)oplane)[ip] = pk;
  }
}

// ------------------- K4b: plane bf16 -> token-major bf16 (roll by `s` fused) ----
// grid 2048 (= b*64 + w), block 256. token (b, w, n) <- plane pixel ((wh*8+i+s)&63, (ww*8+j+s)&63)
__global__ void k_tok(const ushort* __restrict__ H, ushort* __restrict__ T, int s) {
  int bw = blockIdx.x;
  int b = bw >> 6, w = bw & 63, wh = w >> 3, ww = w & 7;
  __shared__ ushort Ts[64][194];
  const ushort* hb = H + (size_t)b * 192 * 4096;
  for (int i = threadIdx.x; i < 64 * 192; i += 256) {
    int ch = i >> 6, n = i & 63;
    int ii = n >> 3, jj = n & 7;
    int hh = ((wh << 3) + ii + s) & 63, wx = ((ww << 3) + jj + s) & 63;
    Ts[n][ch] = hb[(size_t)ch * 4096 + hh * 64 + wx];
  }
  __syncthreads();
  uint* ob = (uint*)(T + (size_t)bw * 64 * 192);
  for (int i = threadIdx.x; i < 64 * 96; i += 256) {
    int n = i / 96, c2 = (i % 96) * 2;
    ob[i] = (uint)Ts[n][c2] | ((uint)Ts[n][c2 + 1] << 16);
  }
}

// ------------------- K5: unified MFMA GEMM (token-major B only) -------------------
// C[m][n] = A[m][k] * B[n][k], A = bf16 weights [Mfull][K], B = bf16 tokens [..][K].
// Block tile 192(m) x 128(tok). B-tile LDS uses 16B-granule xor swizzle:
//   granule G(token,kg) = token*4 + (kg ^ (token&3))  -> conflict-free b128 r/w.
// emode: 0 = bias->bf16 tok-major; 1 = bias+gelu->bf16; 2 = bias+res fp32 window-scatter(shift).
__global__ __launch_bounds__(256) void k_gemm(
    const ushort* __restrict__ A, const ushort* __restrict__ B,
    const float* __restrict__ bias, void* __restrict__ Cdst,
    const float* __restrict__ Res, int K, int Mfull, int emode, int shift) {
  __shared__ ushort Bs[4096];      // 128 tok x 32 k
  __shared__ float Cs[192][68];
  int n0 = blockIdx.x * 128, m0 = blockIdx.y * 192, z = blockIdx.z;
  int tid = threadIdx.x;
  int lane = tid & 63, wv = tid >> 6;
  int wsm = wv & 1, wsn = wv >> 1;
  int lr = lane & 15, lq = lane >> 4;

  f32x4 acc[6][4];
#pragma unroll
  for (int i = 0; i < 6; i++)
#pragma unroll
    for (int j = 0; j < 4; j++) acc[i][j] = 0;

  const ushort* Arow = A + (size_t)(m0 + wsm * 96 + lr) * K + lq * 8;
  const ushort* Btok = B + (size_t)(z * 4096 + n0) * K;

  for (int k0 = 0; k0 < K; k0 += 32) {
    __syncthreads();
#pragma unroll
    for (int u = 0; u < 2; u++) {
      int id = tid + u * 256;
      int row = id >> 2, kg = id & 3;
      int Gr = row * 4 + (kg ^ (row & 3));
      *(uint4*)&Bs[Gr * 8] = *(const uint4*)(Btok + (size_t)row * K + k0 + kg * 8);
    }
    __syncthreads();
    short8 bf[4];
#pragma unroll
    for (int j = 0; j < 4; j++) {
      int tok = wsn * 64 + j * 16 + lr;
      int Gr = tok * 4 + (lq ^ (tok & 3));
      bf[j] = *(const short8*)&Bs[Gr * 8];
    }
#pragma unroll
    for (int i = 0; i < 6; i++) {
      short8 af = *(const short8*)(Arow + (size_t)(i * 16) * K + k0);
#pragma unroll
      for (int j = 0; j < 4; j++)
        acc[i][j] = __builtin_amdgcn_mfma_f32_16x16x32_bf16(af, bf[j], acc[i][j], 0, 0, 0);
    }
  }

  const float* bptr = bias + m0;
  for (int ph = 0; ph < 2; ph++) {
    __syncthreads();
    if (wsn == ph) {
#pragma unroll
      for (int i = 0; i < 6; i++)
#pragma unroll
        for (int j = 0; j < 4; j++) {
          int tokl = j * 16 + lr;
          int f = wsm * 96 + i * 16 + lq * 4;
#pragma unroll
          for (int r = 0; r < 4; r++) Cs[f + r][tokl] = acc[i][j][r];
        }
    }
    __syncthreads();
    if (emode <= 1) {
      int tokbase = z * 4096 + n0 + ph * 64;
      for (int u = tid; u < 768; u += 256) {
        int c4 = (u >> 4) << 2, tq = (u & 15) << 2;
        float4 r0 = *(const float4*)&Cs[c4 + 0][tq];
        float4 r1 = *(const float4*)&Cs[c4 + 1][tq];
        float4 r2 = *(const float4*)&Cs[c4 + 2][tq];
        float4 r3 = *(const float4*)&Cs[c4 + 3][tq];
        float b0 = bptr[c4], b1 = bptr[c4 + 1], b2 = bptr[c4 + 2], b3 = bptr[c4 + 3];
        float vr[4][4] = {{r0.x + b0, r1.x + b1, r2.x + b2, r3.x + b3},
                          {r0.y + b0, r1.y + b1, r2.y + b2, r3.y + b3},
                          {r0.z + b0, r1.z + b1, r2.z + b2, r3.z + b3},
                          {r0.w + b0, r1.w + b1, r2.w + b2, r3.w + b3}};
#pragma unroll
        for (int jj = 0; jj < 4; jj++) {
          float v0 = vr[jj][0], v1 = vr[jj][1], v2 = vr[jj][2], v3 = vr[jj][3];
          if (emode == 1) { v0 = gelu_(v0); v1 = gelu_(v1); v2 = gelu_(v2); v3 = gelu_(v3); }
          ushort4 o = {f2b(v0), f2b(v1), f2b(v2), f2b(v3)};
          *(ushort4*)((ushort*)Cdst + (size_t)(tokbase + tq + jj) * Mfull + m0 + c4) = o;
        }
      }
    } else {
      int tg0 = n0 + ph * 64;
      int w = tg0 >> 6, wh = w >> 3, ww = w & 7;
      for (int u = tid; u < 3072; u += 256) {
        int cc = u >> 4, tq = (u & 15) << 2;
        int ii = tq >> 3, jj4 = tq & 4;
        int hh = ((wh << 3) + ii + shift) & 63;
        int wx = ((ww << 3) + jj4 + shift) & 63;
        size_t addr = ((size_t)z * 192 + cc) * 4096 + hh * 64 + wx;
        float4 rr = *(const float4*)(Res + addr);
        float4 cv = *(const float4*)&Cs[cc][tq];
        float bi = bptr[cc];
        float4 ov = {cv.x + bi + rr.x, cv.y + bi + rr.y, cv.z + bi + rr.z, cv.w + bi + rr.w};
        *(float4*)((float*)Cdst + addr) = ov;
      }
    }
  }
}

// ------------------- K6: windowed attention (bf16 in/out) -------------------
__global__ __launch_bounds__(256) void k_attn(
    const ushort* __restrict__ QKV, const float* __restrict__ rpb,
    ushort* __restrict__ AO) {
  int bw = blockIdx.x, head = blockIdx.y;
  __shared__ float qs[64 * 33], ks[64 * 33], vs[64 * 33];
  __shared__ float ss[64 * 65];
  __shared__ float invs[64];
  const ushort* base = QKV + (size_t)bw * 64 * 576 + head * 32;
  int tid = threadIdx.x;
  {
    int n = tid >> 2, d8 = (tid & 3) << 3;
    const ushort* rp = base + (size_t)n * 576 + d8;
    uint4 qv = *(const uint4*)(rp);
    uint4 kv = *(const uint4*)(rp + 192);
    uint4 vv = *(const uint4*)(rp + 384);
    uint qa[4] = {qv.x, qv.y, qv.z, qv.w};
    uint ka[4] = {kv.x, kv.y, kv.z, kv.w};
    uint va[4] = {vv.x, vv.y, vv.z, vv.w};
    float* qd = &qs[n * 33 + d8];
    float* kd = &ks[n * 33 + d8];
    float* vd = &vs[n * 33 + d8];
#pragma unroll
    for (int i = 0; i < 4; i++) {
      qd[2 * i]     = __uint_as_float(qa[i] << 16) * SCALE_Q;
      qd[2 * i + 1] = __uint_as_float(qa[i] & 0xffff0000u) * SCALE_Q;
      kd[2 * i]     = __uint_as_float(ka[i] << 16);
      kd[2 * i + 1] = __uint_as_float(ka[i] & 0xffff0000u);
      vd[2 * i]     = __uint_as_float(va[i] << 16);
      vd[2 * i + 1] = __uint_as_float(va[i] & 0xffff0000u);
    }
  }
  __syncthreads();
  int tx = tid & 15, ty = tid >> 4;
  float acc[4][4] = {};
#pragma unroll 8
  for (int d = 0; d < 32; d++) {
    float ar[4], br[4];
#pragma unroll
    for (int i = 0; i < 4; i++) ar[i] = qs[(ty * 4 + i) * 33 + d];
#pragma unroll
    for (int j = 0; j < 4; j++) br[j] = ks[(tx * 4 + j) * 33 + d];
#pragma unroll
    for (int i = 0; i < 4; i++)
#pragma unroll
      for (int j = 0; j < 4; j++)
        acc[i][j] = fmaf(ar[i], br[j], acc[i][j]);
  }
  int w = bw & 63, wh = w >> 3, ww = w & 7;
#pragma unroll
  for (int i = 0; i < 4; i++) {
    int n = ty * 4 + i;
    int i1 = n >> 3, j1 = n & 7;
    int g1 = ((wh == 7) ? (i1 < 4 ? 1 : 2) : 0) * 3 + ((ww == 7) ? (j1 < 4 ? 1 : 2) : 0);
#pragma unroll
    for (int j = 0; j < 4; j++) {
      int m = tx * 4 + j;
      int i2 = m >> 3, j2 = m & 7;
      int g2 = ((wh == 7) ? (i2 < 4 ? 1 : 2) : 0) * 3 + ((ww == 7) ? (j2 < 4 ? 1 : 2) : 0);
      float bias = rpb[((i1 - i2 + 7) * 15 + (j1 - j2 + 7)) * 6 + head];
      float mv = (g1 != g2) ? -100.f : 0.f;
      ss[n * 65 + m] = acc[i][j] + bias + mv;
    }
  }
  __syncthreads();
  int row = tid >> 2, qt = tid & 3;
  float mx = -1e30f;
  for (int k = 0; k < 16; k++) mx = fmaxf(mx, ss[row * 65 + qt * 16 + k]);
  mx = fmaxf(mx, __shfl_xor(mx, 1));
  mx = fmaxf(mx, __shfl_xor(mx, 2));
  float sum = 0.f;
  for (int k = 0; k < 16; k++) {
    float e = __expf(ss[row * 65 + qt * 16 + k] - mx);
    ss[row * 65 + qt * 16 + k] = e;
    sum += e;
  }
  sum += __shfl_xor(sum, 1);
  sum += __shfl_xor(sum, 2);
  if (qt == 0) invs[row] = 1.f / sum;
  __syncthreads();
  int tx2 = tid & 7, ty2 = tid >> 3;
  int n0 = ty2 * 2;
  float o0[4] = {}, o1[4] = {};
  for (int m = 0; m < 64; m++) {
    float p0 = ss[n0 * 65 + m], p1 = ss[(n0 + 1) * 65 + m];
#pragma unroll
    for (int dd = 0; dd < 4; dd++) {
      float vvv = vs[m * 33 + tx2 * 4 + dd];
      o0[dd] = fmaf(p0, vvv, o0[dd]);
      o1[dd] = fmaf(p1, vvv, o1[dd]);
    }
  }
  float i0 = invs[n0], i1 = invs[n0 + 1];
  ushort* ob = AO + ((size_t)(bw * 64 + n0)) * 192 + head * 32 + tx2 * 4;
  ushort4 w0 = {f2b(o0[0] * i0), f2b(o0[1] * i0), f2b(o0[2] * i0), f2b(o0[3] * i0)};
  ushort4 w1 = {f2b(o1[0] * i1), f2b(o1[1] * i1), f2b(o1[2] * i1), f2b(o1[3] * i1)};
  *(ushort4*)ob = w0;
  *(ushort4*)(ob + 192) = w1;
}

// ------------------- launch -------------------
extern "C" void kernel_launch(void* const* d_in, const int* in_sizes, int n_in,
                              void* d_out, int out_size, void* d_ws, size_t ws_size,
                              hipStream_t stream) {
  (void)in_sizes; (void)n_in; (void)out_size; (void)ws_size;
  const float* x      = (const float*)d_in[0];
  const float* t      = (const float*)d_in[1];
  const float* n1_w   = (const float*)d_in[2];
  const float* n1_b   = (const float*)d_in[3];
  const float* qkv_w  = (const float*)d_in[4];
  const float* qkv_b  = (const float*)d_in[5];
  const float* rpb    = (const float*)d_in[6];
  const float* proj_w = (const float*)d_in[7];
  const float* proj_b = (const float*)d_in[8];
  const float* n2_w   = (const float*)d_in[9];
  const float* n2_b   = (const float*)d_in[10];
  const float* fc1_w  = (const float*)d_in[11];
  const float* fc1_b  = (const float*)d_in[12];
  const float* fc2_w  = (const float*)d_in[13];
  const float* fc2_b  = (const float*)d_in[14];
  const float* aw_msa = (const float*)d_in[15];
  const float* ab_msa = (const float*)d_in[16];
  const float* aw_mlp = (const float*)d_in[17];
  const float* ab_mlp = (const float*)d_in[18];
  float* out = (float*)d_out;
  float* ws = (float*)d_ws;

  // workspace layout (float offsets): total 76,021,760 floats = 304 MB
  float*  S   = ws;                          // 2560
  float*  Mm  = ws + 4096;                   // 262144
  float*  ST1 = ws + 266240;                 // 2048
  float*  ST2 = ws + 268288;                 // 2048
  ushort* Wq  = (ushort*)(ws + 270336);      // 110592 bf16
  ushort* Wp  = Wq + 110592;                 // 36864
  ushort* W1  = Wp + 36864;                  // 147456
  ushort* W2  = W1 + 147456;                 // 147456
  ushort* Hbf = (ushort*)(ws + 524288);      // 25165824 bf16 plane-major
  ushort* T   = (ushort*)(ws + 13107200);    // 25165824 bf16 token-major
  ushort* QKV = (ushort*)(ws + 25690112);    // 75497472 bf16
  ushort* AO  = (ushort*)(ws + 63438848);    // 25165824 bf16
  ushort* G   = QKV;                         // 100663296 bf16, aliases QKV+AO (both dead)

  k_scales<<<dim3(32, 2), 64, 0, stream>>>(t, aw_msa, ab_msa, aw_mlp, ab_mlp, S);
  k_mbuild<<<dim3(32, 2), 256, 0, stream>>>(S, Mm);
  k_f2b<<<432, 256, 0, stream>>>(qkv_w, proj_w, fc1_w, fc2_w, Wq, Wp, W1, W2);

  // ---- attention branch ----
  k_gnstats<<<1024, 256, 0, stream>>>(x, ST1);
  k_gn_adafm<<<dim3(192, 32), 256, 0, stream>>>(x, ST1, n1_w, n1_b, Mm, Hbf);
  k_tok<<<2048, 256, 0, stream>>>(Hbf, T, 4);
  k_gemm<<<dim3(32, 3, 32), 256, 0, stream>>>(Wq, T, qkv_b, QKV, nullptr, 192, 576, 0, 0);
  k_attn<<<dim3(2048, 6), 256, 0, stream>>>(QKV, rpb, AO);
  k_gemm<<<dim3(32, 1, 32), 256, 0, stream>>>(Wp, AO, proj_b, out, x, 192, 192, 2, 4);

  // ---- MLP branch ----
  k_gnstats<<<1024, 256, 0, stream>>>(out, ST2);
  k_gn_adafm<<<dim3(192, 32), 256, 0, stream>>>(out, ST2, n2_w, n2_b, Mm + 131072, Hbf);
  k_tok<<<2048, 256, 0, stream>>>(Hbf, T, 0);
  k_gemm<<<dim3(32, 4, 32), 256, 0, stream>>>(W1, T, fc1_b, G, nullptr, 192, 768, 1, 0);
  k_gemm<<<dim3(32, 1, 32), 256, 0, stream>>>(W2, G, fc2_b, out, out, 768, 192, 2, 0);
}